// Round 6
// baseline (87.219 us; speedup 1.0000x reference)
//
#include <hip/hip_runtime.h>

#define N_VERT 163842
#define N8_X   1310736              // N_VERT*64/8
#define NBLK   512                  // 2 blocks/CU, all resident (one round)

typedef float  f32x4  __attribute__((ext_vector_type(4)));
typedef short  s16x8  __attribute__((ext_vector_type(8)));

__device__ __forceinline__ unsigned short f2bf(float f) {
  union { float f; unsigned int u; } c; c.f = f;
  unsigned int u = c.u;
  u += 0x7FFFu + ((u >> 16) & 1u);   // RNE truncate to bf16
  return (unsigned short)(u >> 16);
}

__device__ __forceinline__ s16x8 cvt8(const f32x4 a, const f32x4 b) {
  s16x8 h;
  h[0] = (short)f2bf(a[0]); h[1] = (short)f2bf(a[1]);
  h[2] = (short)f2bf(a[2]); h[3] = (short)f2bf(a[3]);
  h[4] = (short)f2bf(b[0]); h[5] = (short)f2bf(b[1]);
  h[6] = (short)f2bf(b[2]); h[7] = (short)f2bf(b[3]);
  return h;
}

__global__ void detect64(const unsigned int* __restrict__ hexw, int* __restrict__ flag) {
  __shared__ int any;
  if (threadIdx.x == 0) any = 0;
  __syncthreads();
  if (hexw[2 * threadIdx.x + 1] != 0u) any = 1;
  __syncthreads();
  if (threadIdx.x == 0) *flag = (any == 0) ? 1 : 0;   // 1 => int64, 0 => int32
}

// Fused prep: detect (block 0) + W->Wf frag-layout bf16 (blocks 1..112) + x->xbf.
// Wf byte layout: frag(ks,hi,col) at ks*4096 + hi*1024 + col*16.
__global__ __launch_bounds__(256) void prep(
    const float* __restrict__ x, const unsigned int* __restrict__ hexw,
    const float* __restrict__ W,
    unsigned short* __restrict__ Wf, unsigned short* __restrict__ xbf,
    int* __restrict__ flag)
{
  const int b = blockIdx.x, tid = threadIdx.x;

  if (b == 0) {
    __shared__ int any;
    if (tid == 0) any = 0;
    __syncthreads();
    if (hexw[2 * tid + 1] != 0u) any = 1;
    __syncthreads();
    if (tid == 0) *flag = (any == 0) ? 1 : 0;
  }
  if (b >= 1 && b <= 112) {                  // 112*256 = 28672 = 448*64
    const int t   = (b - 1) * 256 + tid;
    const int e   = t & 7;
    const int col = (t >> 3) & 63;
    const int hi  = (t >> 9) & 3;
    const int ks  = t >> 11;
    Wf[t] = f2bf(W[(ks * 32 + hi * 8 + e) * 64 + col]);
  }
  const int stride = gridDim.x * 256;
  for (int i = b * 256 + tid; i < N8_X; i += stride) {
    const f32x4* s = (const f32x4*)(x + (size_t)i * 8);
    *(s16x8*)(xbf + (size_t)i * 8) = cvt8(s[0], s[1]);
  }
}

// R6 == R5 structure; register-cap fix: amdgpu_waves_per_eu(4) -> 128 VGPR cap
// (R4/R5's __launch_bounds__(512,4) was interpreted as 4 blocks/CU -> 64-VGPR
//  cap -> every pipeline slot spilled to scratch: WRITE_SIZE 181 MB vs 41 MB).
template <int BF>
__global__ __launch_bounds__(512) __attribute__((amdgpu_waves_per_eu(4))) void hexconv6(
    const void* __restrict__ xsrc,
    const unsigned int* __restrict__ hexw,
    const void* __restrict__ wsrc,
    const float* __restrict__ bias,
    float* __restrict__ out,
    const int* __restrict__ flag)
{
  __shared__ unsigned short Wl[28672];        // 57344 B -> exactly 2 blocks/CU

  const int tid = threadIdx.x;
  const int wv  = tid >> 6;
  const int ln  = tid & 63;
  const int lo  = ln & 15;
  const int hi  = ln >> 4;
  const int is64 = flag ? *flag : 1;

  // ---- stage W into LDS (frag layout), once; the only barrier
  if (BF) {
    const s16x8* wsv = (const s16x8*)wsrc;
#pragma unroll
    for (int it = 0; it < 7; ++it)
      ((s16x8*)Wl)[it * 512 + tid] = wsv[it * 512 + tid];
  } else {
    const float* W = (const float*)wsrc;
    for (int it = 0; it < 56; ++it) {
      const int t   = it * 512 + tid;
      const int e   = t & 7;
      const int col = (t >> 3) & 63;
      const int hif = (t >> 9) & 3;
      const int ks  = t >> 11;
      Wl[t] = f2bf(W[(ks * 32 + hif * 8 + e) * 64 + col]);
    }
  }
  __syncthreads();

  const char* xbase = (const char*)xsrc;
  const char* Wb    = (const char*)Wl + (hi * 64 + lo) * 16;

  float bval[4];
#pragma unroll
  for (int nt = 0; nt < 4; ++nt) bval[nt] = bias[nt * 16 + lo];

  // ---- static tile schedule: block owns 320 rows = 20 tiles of 16.
  // waves 0-3: 3 tiles, waves 4-7: 2 tiles; block 511 wave 3 gets tile 10240.
  const int b = blockIdx.x;
  const int twbase = (wv < 4) ? 3 * wv : 12 + 2 * (wv - 4);
  const bool special = (b == NBLK - 1) && (wv == 3);
  const int ntile = special ? 4 : ((wv < 4) ? 3 : 2);
  const int rb0 = b * 320 + twbase * 16;
  const int rb1 = rb0 + 16, rb2 = rb0 + 32;
  const int rb3 = special ? 163840 : rb0 + 48;

  const int shf = 2 + is64;                   // bytes per index: 4 or 8
  const int obs = BF ? 7 : 8;                 // idx -> byte offset shift

#define LOAD_OFF(dst, rb_)                                                     \
  do {                                                                         \
    int rr = (rb_) + lo;                                                       \
    rr = (rr < N_VERT) ? rr : (N_VERT - 1);                                    \
    const char* ip = (const char*)hexw + ((size_t)((unsigned)rr * 7u) << shf); \
    _Pragma("unroll")                                                          \
    for (int j = 0; j < 7; ++j)                                                \
      (dst)[j] = (*(const unsigned int*)(ip + ((size_t)j << shf))) << obs;     \
  } while (0)

#define LOAD_A(S, OFF, jj)                                                     \
  do {                                                                         \
    const char* p = xbase + (size_t)(OFF)[jj];                                 \
    if (BF) {                                                                  \
      S##_0 = *(const s16x8*)(p + hi * 16);                                    \
      S##_1 = *(const s16x8*)(p + 64 + hi * 16);                               \
    } else {                                                                   \
      const f32x4* q0 = (const f32x4*)(p + hi * 32);                           \
      S##_0 = cvt8(q0[0], q0[1]);                                              \
      S##_1 = cvt8(*(const f32x4*)(p + 128 + hi * 32),                         \
                   *(const f32x4*)(p + 144 + hi * 32));                        \
    }                                                                          \
  } while (0)

#define MFMA_J(jj, S)                                                          \
  do {                                                                         \
    _Pragma("unroll")                                                          \
    for (int nt = 0; nt < 4; ++nt) {                                           \
      const s16x8 bf0 = *(const s16x8*)(Wb + (2 * (jj)) * 4096 + nt * 256);    \
      acc[nt] = __builtin_amdgcn_mfma_f32_16x16x32_bf16(S##_0, bf0, acc[nt], 0, 0, 0); \
    }                                                                          \
    _Pragma("unroll")                                                          \
    for (int nt = 0; nt < 4; ++nt) {                                           \
      const s16x8 bf1 = *(const s16x8*)(Wb + (2 * (jj) + 1) * 4096 + nt * 256);\
      acc[nt] = __builtin_amdgcn_mfma_f32_16x16x32_bf16(S##_1, bf1, acc[nt], 0, 0, 0); \
    }                                                                          \
  } while (0)

// One 16-row tile. PRE (uniform): reissue slots for next tile from OFFN.
// IDX (uniform): load tile-(t+2) offsets into OFFPRE at tile top.
#define TILE(RB, OFFN, PRE, OFFPRE, RBPRE, IDX)                                \
  do {                                                                         \
    if (IDX) LOAD_OFF(OFFPRE, RBPRE);                                          \
    _Pragma("unroll")                                                          \
    for (int nt = 0; nt < 4; ++nt) acc[nt] = (f32x4){0.f, 0.f, 0.f, 0.f};      \
    if (PRE) {                                                                 \
      MFMA_J(0, s0); LOAD_A(s0, OFFN, 0);                                      \
      MFMA_J(1, s1); LOAD_A(s1, OFFN, 1);                                      \
      MFMA_J(2, s2); LOAD_A(s2, OFFN, 2);                                      \
      MFMA_J(3, s3); LOAD_A(s3, OFFN, 3);                                      \
      MFMA_J(4, s4); LOAD_A(s4, OFFN, 4);                                      \
      MFMA_J(5, s5); LOAD_A(s5, OFFN, 5);                                      \
      MFMA_J(6, s6); LOAD_A(s6, OFFN, 6);                                      \
    } else {                                                                   \
      MFMA_J(0, s0); MFMA_J(1, s1); MFMA_J(2, s2); MFMA_J(3, s3);              \
      MFMA_J(4, s4); MFMA_J(5, s5); MFMA_J(6, s6);                             \
    }                                                                          \
    _Pragma("unroll")                                                          \
    for (int i = 0; i < 4; ++i) {                                              \
      const int row = (RB) + hi * 4 + i;                                       \
      if (row < N_VERT) {                                                      \
        float* orow = out + (size_t)row * 64;                                  \
        _Pragma("unroll")                                                      \
        for (int nt = 0; nt < 4; ++nt) orow[nt * 16 + lo] = acc[nt][i] + bval[nt]; \
      }                                                                        \
    }                                                                          \
  } while (0)

  unsigned int offA[7], offB[7];
  s16x8 s0_0, s0_1, s1_0, s1_1, s2_0, s2_1, s3_0, s3_1,
        s4_0, s4_1, s5_0, s5_1, s6_0, s6_1;
  f32x4 acc[4];

  // prologue: tile0 offsets + all 7 fragment pairs in flight; tile1 offsets
  LOAD_OFF(offA, rb0);
  LOAD_A(s0, offA, 0); LOAD_A(s1, offA, 1); LOAD_A(s2, offA, 2);
  LOAD_A(s3, offA, 3); LOAD_A(s4, offA, 4); LOAD_A(s5, offA, 5);
  LOAD_A(s6, offA, 6);
  LOAD_OFF(offB, rb1);                       // rb1 always a valid row range

  TILE(rb0, offB, (ntile > 1), offA, rb2, (ntile > 2));
  if (ntile > 1) TILE(rb1, offA, (ntile > 2), offB, rb3, (ntile > 3));
  if (ntile > 2) TILE(rb2, offB, (ntile > 3), offA, rb0, 0);
  if (ntile > 3) TILE(rb3, offA, 0, offB, rb0, 0);

#undef LOAD_OFF
#undef LOAD_A
#undef MFMA_J
#undef TILE
}

extern "C" void kernel_launch(void* const* d_in, const int* in_sizes, int n_in,
                              void* d_out, int out_size, void* d_ws, size_t ws_size,
                              hipStream_t stream) {
  const float*        x    = (const float*)d_in[0];
  const unsigned int* hexw = (const unsigned int*)d_in[1];
  const float*        W    = (const float*)d_in[2];
  const float*        b    = (const float*)d_in[3];
  float*              out  = (float*)d_out;

  const size_t WS_NEED = 65536 + (size_t)N_VERT * 64 * 2;

  if (ws_size >= WS_NEED) {
    int*            flag = (int*)d_ws;
    unsigned short* Wf   = (unsigned short*)((char*)d_ws + 4096);
    unsigned short* xbf  = (unsigned short*)((char*)d_ws + 65536);
    prep<<<2048, 256, 0, stream>>>(x, hexw, W, Wf, xbf, flag);
    hexconv6<1><<<NBLK, 512, 0, stream>>>(xbf, hexw, Wf, b, out, flag);
  } else {
    int* flag = (ws_size >= 4) ? (int*)d_ws : nullptr;
    if (flag) detect64<<<1, 256, 0, stream>>>(hexw, flag);
    hexconv6<0><<<NBLK, 512, 0, stream>>>(x, hexw, W, b, out, flag);
  }
}

// Round 7
// 45.497 us; speedup vs baseline: 1.9170x; 1.9170x over previous
//
#include <hip/hip_runtime.h>

#define N_VERT 163842
#define N8_X   1310736              // N_VERT*64/8
#define NBLK   512                  // 2 blocks/CU, one full round
#define ROWS_PER_BLK 320

typedef float  f32x4  __attribute__((ext_vector_type(4)));
typedef short  s16x8  __attribute__((ext_vector_type(8)));

__device__ __forceinline__ unsigned short f2bf(float f) {
  union { float f; unsigned int u; } c; c.f = f;
  unsigned int u = c.u;
  u += 0x7FFFu + ((u >> 16) & 1u);   // RNE truncate to bf16
  return (unsigned short)(u >> 16);
}

__device__ __forceinline__ s16x8 cvt8(const f32x4 a, const f32x4 b) {
  s16x8 h;
  h[0] = (short)f2bf(a[0]); h[1] = (short)f2bf(a[1]);
  h[2] = (short)f2bf(a[2]); h[3] = (short)f2bf(a[3]);
  h[4] = (short)f2bf(b[0]); h[5] = (short)f2bf(b[1]);
  h[6] = (short)f2bf(b[2]); h[7] = (short)f2bf(b[3]);
  return h;
}

__global__ void detect64(const unsigned int* __restrict__ hexw, int* __restrict__ flag) {
  __shared__ int any;
  if (threadIdx.x == 0) any = 0;
  __syncthreads();
  if (hexw[2 * threadIdx.x + 1] != 0u) any = 1;
  __syncthreads();
  if (threadIdx.x == 0) *flag = (any == 0) ? 1 : 0;   // 1 => int64, 0 => int32
}

// Fused prep: detect (block 0) + W->Wf frag-layout bf16 (blocks 1..112) + x->xbf.
// Wf byte layout: frag(ks,hi,col) at ks*4096 + hi*1024 + col*16.
__global__ __launch_bounds__(256) void prep(
    const float* __restrict__ x, const unsigned int* __restrict__ hexw,
    const float* __restrict__ W,
    unsigned short* __restrict__ Wf, unsigned short* __restrict__ xbf,
    int* __restrict__ flag)
{
  const int b = blockIdx.x, tid = threadIdx.x;

  if (b == 0) {
    __shared__ int any;
    if (tid == 0) any = 0;
    __syncthreads();
    if (hexw[2 * tid + 1] != 0u) any = 1;
    __syncthreads();
    if (tid == 0) *flag = (any == 0) ? 1 : 0;
  }
  if (b >= 1 && b <= 112) {                  // 112*256 = 28672 = 448*64
    const int t   = (b - 1) * 256 + tid;
    const int e   = t & 7;
    const int col = (t >> 3) & 63;
    const int hi  = (t >> 9) & 3;
    const int ks  = t >> 11;
    Wf[t] = f2bf(W[(ks * 32 + hi * 8 + e) * 64 + col]);
  }
  const int stride = gridDim.x * 256;
  for (int i = b * 256 + tid; i < N8_X; i += stride) {
    const f32x4* s = (const f32x4*)(x + (size_t)i * 8);
    *(s16x8*)(xbf + (size_t)i * 8) = cvt8(s[0], s[1]);
  }
}

// R7: 256-thread blocks (escapes the 512-thr 64-VGPR allocator cap that made
// R4-R6 spill 140 MB to scratch). W in LDS (57.3 KB, 2 blocks/CU), zero inner
// barriers, 32-row chunks (B-frag reads shared by two row-sets), depth-2
// statically-named pipeline with cross-chunk offset + j0 prefetch.
template <int BF>
__global__ __launch_bounds__(256) void hexconv7(
    const void* __restrict__ xsrc,
    const unsigned int* __restrict__ hexw,
    const void* __restrict__ wsrc,
    const float* __restrict__ bias,
    float* __restrict__ out,
    const int* __restrict__ flag)
{
  __shared__ unsigned short Wl[28672];        // 57344 B

  const int tid = threadIdx.x;
  const int wv  = tid >> 6;                   // wave 0..3
  const int ln  = tid & 63;
  const int lo  = ln & 15;
  const int hi  = ln >> 4;
  const int is64 = flag ? *flag : 1;

  // ---- stage W into LDS (frag layout); the only barrier
  if (BF) {
    const s16x8* wsv = (const s16x8*)wsrc;
#pragma unroll
    for (int it = 0; it < 14; ++it)
      ((s16x8*)Wl)[it * 256 + tid] = wsv[it * 256 + tid];
  } else {
    const float* W = (const float*)wsrc;
    for (int it = 0; it < 112; ++it) {
      const int t   = it * 256 + tid;
      const int e   = t & 7;
      const int col = (t >> 3) & 63;
      const int hif = (t >> 9) & 3;
      const int ks  = t >> 11;
      Wl[t] = f2bf(W[(ks * 32 + hif * 8 + e) * 64 + col]);
    }
  }
  __syncthreads();

  const char* xbase = (const char*)xsrc;
  const char* hexb  = (const char*)hexw;
  const char* Wb    = (const char*)Wl + (hi * 64 + lo) * 16;

  float bval[4];
#pragma unroll
  for (int nt = 0; nt < 4; ++nt) bval[nt] = bias[nt * 16 + lo];

  // ---- schedule: block owns 320 rows; waves 0-1: 3 chunks, waves 2-3: 2.
  // Block 511 wave 2 gets a guarded 3rd chunk at row 163840 (2-row tail).
  const int B0 = blockIdx.x * ROWS_PER_BLK;
  const int base3 = (wv < 2) ? wv * 96 : 192 + (wv - 2) * 64;
  const int rb0 = B0 + base3;
  const int rb1 = rb0 + 32;
  const bool special = (blockIdx.x == NBLK - 1) && (wv == 2);
  const bool three = (wv < 2) || special;
  const int rb2 = special ? 163840 : rb0 + 64;

  const int shf = 2 + is64;                   // bytes per index: 4 or 8
  const int obs = BF ? 7 : 8;                 // idx -> row byte offset shift

#define LOAD_OFF(O0, O1, rb_)                                                  \
  do {                                                                         \
    int ra = (rb_) + lo;        ra = (ra < N_VERT) ? ra : (N_VERT - 1);        \
    int rbx = (rb_) + 16 + lo;  rbx = (rbx < N_VERT) ? rbx : (N_VERT - 1);     \
    const char* ipa = hexb + ((size_t)((unsigned)ra * 7u) << shf);             \
    const char* ipb = hexb + ((size_t)((unsigned)rbx * 7u) << shf);            \
    _Pragma("unroll")                                                          \
    for (int j = 0; j < 7; ++j) {                                              \
      (O0)[j] = (*(const unsigned int*)(ipa + ((size_t)j << shf))) << obs;     \
      (O1)[j] = (*(const unsigned int*)(ipb + ((size_t)j << shf))) << obs;     \
    }                                                                          \
  } while (0)

// slot S = 4 s16x8: S##00 (row0,k-lo), S##01 (row0,k-hi), S##10, S##11 (row1)
#define LOAD_S(S, O0, O1, jj)                                                  \
  do {                                                                         \
    const char* p0 = xbase + (size_t)(O0)[jj];                                 \
    const char* p1 = xbase + (size_t)(O1)[jj];                                 \
    if (BF) {                                                                  \
      S##00 = *(const s16x8*)(p0 + hi * 16);                                   \
      S##01 = *(const s16x8*)(p0 + 64 + hi * 16);                              \
      S##10 = *(const s16x8*)(p1 + hi * 16);                                   \
      S##11 = *(const s16x8*)(p1 + 64 + hi * 16);                              \
    } else {                                                                   \
      const f32x4* q0 = (const f32x4*)(p0 + hi * 32);                          \
      const f32x4* q1 = (const f32x4*)(p1 + hi * 32);                          \
      S##00 = cvt8(q0[0], q0[1]);                                              \
      S##01 = cvt8(*(const f32x4*)(p0 + 128 + hi * 32),                        \
                   *(const f32x4*)(p0 + 144 + hi * 32));                       \
      S##10 = cvt8(q1[0], q1[1]);                                              \
      S##11 = cvt8(*(const f32x4*)(p1 + 128 + hi * 32),                        \
                   *(const f32x4*)(p1 + 144 + hi * 32));                       \
    }                                                                          \
  } while (0)

#define MFMA_J(jj, S)                                                          \
  do {                                                                         \
    _Pragma("unroll")                                                          \
    for (int nt = 0; nt < 4; ++nt) {                                           \
      const s16x8 bf0 = *(const s16x8*)(Wb + (2 * (jj)) * 4096 + nt * 256);    \
      acc0[nt] = __builtin_amdgcn_mfma_f32_16x16x32_bf16(S##00, bf0, acc0[nt], 0, 0, 0); \
      acc1[nt] = __builtin_amdgcn_mfma_f32_16x16x32_bf16(S##10, bf0, acc1[nt], 0, 0, 0); \
    }                                                                          \
    _Pragma("unroll")                                                          \
    for (int nt = 0; nt < 4; ++nt) {                                           \
      const s16x8 bf1 = *(const s16x8*)(Wb + (2 * (jj) + 1) * 4096 + nt * 256);\
      acc0[nt] = __builtin_amdgcn_mfma_f32_16x16x32_bf16(S##01, bf1, acc0[nt], 0, 0, 0); \
      acc1[nt] = __builtin_amdgcn_mfma_f32_16x16x32_bf16(S##11, bf1, acc1[nt], 0, 0, 0); \
    }                                                                          \
  } while (0)

#define STORES(RB)                                                             \
  do {                                                                         \
    _Pragma("unroll")                                                          \
    for (int i = 0; i < 4; ++i) {                                              \
      const int row0 = (RB) + hi * 4 + i;                                      \
      if (row0 < N_VERT) {                                                     \
        float* orow = out + (size_t)row0 * 64;                                 \
        _Pragma("unroll")                                                      \
        for (int nt = 0; nt < 4; ++nt) orow[nt * 16 + lo] = acc0[nt][i] + bval[nt]; \
      }                                                                        \
      const int row1 = (RB) + 16 + hi * 4 + i;                                 \
      if (row1 < N_VERT) {                                                     \
        float* orow = out + (size_t)row1 * 64;                                 \
        _Pragma("unroll")                                                      \
        for (int nt = 0; nt < 4; ++nt) orow[nt * 16 + lo] = acc1[nt][i] + bval[nt]; \
      }                                                                        \
    }                                                                          \
  } while (0)

// One 32-row chunk. Entry invariant: ENT holds j0 frags of chunk RB.
// DO_NOFF (uniform): load next chunk's offsets into ON0/ON1 early.
// DO_NA (uniform): load next chunk's j0 frags into ALT at the end.
#define CHUNK(RB, ENT, ALT, OC0, OC1, DO_NOFF, ON0, ON1, RBN, DO_NA)           \
  do {                                                                         \
    _Pragma("unroll")                                                          \
    for (int nt = 0; nt < 4; ++nt) { acc0[nt] = (f32x4){0,0,0,0}; acc1[nt] = (f32x4){0,0,0,0}; } \
    LOAD_S(ALT, OC0, OC1, 1);                                                  \
    if (DO_NOFF) LOAD_OFF(ON0, ON1, RBN);                                      \
    MFMA_J(0, ENT);  LOAD_S(ENT, OC0, OC1, 2);                                 \
    MFMA_J(1, ALT);  LOAD_S(ALT, OC0, OC1, 3);                                 \
    MFMA_J(2, ENT);  LOAD_S(ENT, OC0, OC1, 4);                                 \
    MFMA_J(3, ALT);  LOAD_S(ALT, OC0, OC1, 5);                                 \
    MFMA_J(4, ENT);  LOAD_S(ENT, OC0, OC1, 6);                                 \
    MFMA_J(5, ALT);                                                            \
    if (DO_NA) LOAD_S(ALT, ON0, ON1, 0);                                       \
    MFMA_J(6, ENT);                                                            \
    STORES(RB);                                                                \
  } while (0)

  unsigned int offA0[7], offA1[7], offB0[7], offB1[7];
  s16x8 sA00, sA01, sA10, sA11, sB00, sB01, sB10, sB11;
  f32x4 acc0[4], acc1[4];

  // prologue: chunk0 offsets + j0 frags
  LOAD_OFF(offA0, offA1, rb0);
  LOAD_S(sA, offA0, offA1, 0);

  CHUNK(rb0, sA, sB, offA0, offA1, true, offB0, offB1, rb1, true);
  CHUNK(rb1, sB, sA, offB0, offB1, three, offA0, offA1, rb2, three);
  if (three)
    CHUNK(rb2, sA, sB, offA0, offA1, false, offB0, offB1, rb2, false);

#undef LOAD_OFF
#undef LOAD_S
#undef MFMA_J
#undef STORES
#undef CHUNK
}

extern "C" void kernel_launch(void* const* d_in, const int* in_sizes, int n_in,
                              void* d_out, int out_size, void* d_ws, size_t ws_size,
                              hipStream_t stream) {
  const float*        x    = (const float*)d_in[0];
  const unsigned int* hexw = (const unsigned int*)d_in[1];
  const float*        W    = (const float*)d_in[2];
  const float*        b    = (const float*)d_in[3];
  float*              out  = (float*)d_out;

  const size_t WS_NEED = 65536 + (size_t)N_VERT * 64 * 2;

  if (ws_size >= WS_NEED) {
    int*            flag = (int*)d_ws;
    unsigned short* Wf   = (unsigned short*)((char*)d_ws + 4096);
    unsigned short* xbf  = (unsigned short*)((char*)d_ws + 65536);
    prep<<<2048, 256, 0, stream>>>(x, hexw, W, Wf, xbf, flag);
    hexconv7<1><<<NBLK, 256, 0, stream>>>(xbf, hexw, Wf, b, out, flag);
  } else {
    int* flag = (ws_size >= 4) ? (int*)d_ws : nullptr;
    if (flag) detect64<<<1, 256, 0, stream>>>(hexw, flag);
    hexconv7<0><<<NBLK, 256, 0, stream>>>(x, hexw, W, b, out, flag);
  }
}